// Round 1
// baseline (1615.019 us; speedup 1.0000x reference)
//
#include <hip/hip_runtime.h>
#include <hip/hip_bf16.h>
#include <math.h>

// Problem constants (from reference):
// N=20000, IN_F=256, HID=128, HEADS=4, OUT_F=10, E=400000, G=64, HC=512
#define NODES   20000
#define IN_F    256
#define HID     128
#define HEADS   4
#define OUT_F   10
#define NEDGE   400000
#define NGRAPH  64
#define HC      512
#define EPRIME  (NEDGE + NODES)   // with self loops

// ---------------------------------------------------------------------------
// Edge preprocessing: counting sort by dst
// ---------------------------------------------------------------------------
__global__ __launch_bounds__(256) void hist_kernel(const int* __restrict__ ei,
                                                   int* __restrict__ counts) {
    int e = blockIdx.x * blockDim.x + threadIdx.x;
    if (e >= EPRIME) return;
    int dst = (e < NEDGE) ? ei[NEDGE + e] : (e - NEDGE);
    atomicAdd(&counts[dst], 1);
}

__global__ __launch_bounds__(1024) void scan_kernel(const int* __restrict__ counts,
                                                    int* __restrict__ offsets,
                                                    int* __restrict__ cursor) {
    __shared__ int wsum[16];
    __shared__ int s_carry;
    const int tid = threadIdx.x;
    const int lane = tid & 63, wid = tid >> 6;
    if (tid == 0) s_carry = 0;
    __syncthreads();
    for (int base = 0; base < NODES; base += 1024) {
        int idx = base + tid;
        int v = (idx < NODES) ? counts[idx] : 0;
        int x = v;
        #pragma unroll
        for (int d = 1; d < 64; d <<= 1) {
            int n = __shfl_up(x, d);
            if (lane >= d) x += n;
        }
        if (lane == 63) wsum[wid] = x;
        __syncthreads();
        if (wid == 0) {
            int w = (lane < 16) ? wsum[lane] : 0;
            #pragma unroll
            for (int d = 1; d < 16; d <<= 1) {
                int n = __shfl_up(w, d);
                if (lane >= d) w += n;
            }
            if (lane < 16) wsum[lane] = w;
        }
        __syncthreads();
        int carry = s_carry;
        int wpre = (wid == 0) ? 0 : wsum[wid - 1];
        int excl = carry + wpre + x - v;
        if (idx < NODES) { offsets[idx] = excl; cursor[idx] = excl; }
        __syncthreads();
        if (tid == 1023) s_carry = carry + wsum[15];
        __syncthreads();
    }
    if (tid == 0) offsets[NODES] = s_carry;
}

__global__ __launch_bounds__(256) void scatter_kernel(const int* __restrict__ ei,
                                                      int* __restrict__ cursor,
                                                      int* __restrict__ srcs) {
    int e = blockIdx.x * blockDim.x + threadIdx.x;
    if (e >= EPRIME) return;
    int src, dst;
    if (e < NEDGE) { src = ei[e]; dst = ei[NEDGE + e]; }
    else           { src = dst = e - NEDGE; }
    int pos = atomicAdd(&cursor[dst], 1);
    srcs[pos] = src;
}

// ---------------------------------------------------------------------------
// f32 GEMM:  C[M,N] = A[M,K] @ B[K,N] + bias[N], optional ELU.
// 128x128 tile, BK=16, 256 threads, 8x8 per thread (split 4+4 halves so
// ds_read_b128 across tx is 2-way (free) instead of 4-way).
// N must be a multiple of 128; K a multiple of 16. M guarded.
// ---------------------------------------------------------------------------
#define BM 128
#define BN 128
#define BKk 16

template <int ACT>
__global__ __launch_bounds__(256) void gemm_bias(const float* __restrict__ A,
                                                 const float* __restrict__ B,
                                                 const float* __restrict__ bias,
                                                 float* __restrict__ C,
                                                 int M, int N, int K) {
    __shared__ float As[BKk][BM + 4];
    __shared__ float Bs[BKk][BN + 4];
    const int tid = threadIdx.x;
    const int tx = tid & 15, ty = tid >> 4;
    const int row0 = blockIdx.x * BM, col0 = blockIdx.y * BN;
    const int m0 = ty * 4, n0 = tx * 4;

    float acc[8][8];
    #pragma unroll
    for (int i = 0; i < 8; ++i)
        #pragma unroll
        for (int j = 0; j < 8; ++j) acc[i][j] = 0.f;

    for (int k0 = 0; k0 < K; k0 += BKk) {
        // stage A: 128 rows x 16 k  (transposed into As[k][m])
        #pragma unroll
        for (int q = 0; q < 2; ++q) {
            int qid = tid + q * 256;
            int r = qid >> 2, kq = (qid & 3) << 2;
            int grow = row0 + r;
            float4 v = make_float4(0.f, 0.f, 0.f, 0.f);
            if (grow < M)
                v = *reinterpret_cast<const float4*>(&A[(size_t)grow * K + k0 + kq]);
            As[kq + 0][r] = v.x; As[kq + 1][r] = v.y;
            As[kq + 2][r] = v.z; As[kq + 3][r] = v.w;
        }
        // stage B: 16 k x 128 cols
        #pragma unroll
        for (int q = 0; q < 2; ++q) {
            int qid = tid + q * 256;
            int kk = qid >> 5, c4 = (qid & 31) << 2;
            float4 v = *reinterpret_cast<const float4*>(&B[(size_t)(k0 + kk) * N + col0 + c4]);
            *reinterpret_cast<float4*>(&Bs[kk][c4]) = v;
        }
        __syncthreads();
        #pragma unroll
        for (int kk = 0; kk < BKk; ++kk) {
            float4 a0 = *reinterpret_cast<const float4*>(&As[kk][m0]);
            float4 a1 = *reinterpret_cast<const float4*>(&As[kk][m0 + 64]);
            float4 b0 = *reinterpret_cast<const float4*>(&Bs[kk][n0]);
            float4 b1 = *reinterpret_cast<const float4*>(&Bs[kk][n0 + 64]);
            float a[8] = {a0.x, a0.y, a0.z, a0.w, a1.x, a1.y, a1.z, a1.w};
            float b[8] = {b0.x, b0.y, b0.z, b0.w, b1.x, b1.y, b1.z, b1.w};
            #pragma unroll
            for (int i = 0; i < 8; ++i)
                #pragma unroll
                for (int j = 0; j < 8; ++j) acc[i][j] += a[i] * b[j];
        }
        __syncthreads();
    }

    // epilogue (two row-halves x two col-halves, float4 stores)
    #pragma unroll
    for (int ih = 0; ih < 2; ++ih) {
        #pragma unroll
        for (int i = 0; i < 4; ++i) {
            int r = row0 + ih * 64 + m0 + i;
            if (r >= M) continue;
            #pragma unroll
            for (int jh = 0; jh < 2; ++jh) {
                int c = col0 + jh * 64 + n0;
                float4 bv = *reinterpret_cast<const float4*>(&bias[c]);
                float4 o;
                o.x = acc[ih * 4 + i][jh * 4 + 0] + bv.x;
                o.y = acc[ih * 4 + i][jh * 4 + 1] + bv.y;
                o.z = acc[ih * 4 + i][jh * 4 + 2] + bv.z;
                o.w = acc[ih * 4 + i][jh * 4 + 3] + bv.w;
                if (ACT) {
                    o.x = o.x > 0.f ? o.x : expm1f(o.x);
                    o.y = o.y > 0.f ? o.y : expm1f(o.y);
                    o.z = o.z > 0.f ? o.z : expm1f(o.z);
                    o.w = o.w > 0.f ? o.w : expm1f(o.w);
                }
                *reinterpret_cast<float4*>(&C[(size_t)r * N + c]) = o;
            }
        }
    }
}

// ---------------------------------------------------------------------------
// Fused GATv2 edge kernel: per node, per head. One block per node,
// wave w handles head w, lanes hold 2 channels each (128 ch / 64 lanes).
// Online softmax over incoming edges in chunks -> no global scratch/atomics.
// Epilogue: /denom + bias + ELU, writes h_out.
// ---------------------------------------------------------------------------
#define ECHUNK 128

__global__ __launch_bounds__(256) void gat_edge_kernel(const float* __restrict__ xl,
                                                       const float* __restrict__ xr,
                                                       const float* __restrict__ att,
                                                       const float* __restrict__ bias,
                                                       const int* __restrict__ offsets,
                                                       const int* __restrict__ srcs,
                                                       float* __restrict__ hout) {
    const int node = blockIdx.x;
    const int h = threadIdx.x >> 6;     // head = wave id
    const int lane = threadIdx.x & 63;
    const int c0 = lane * 2;

    __shared__ float s_logit[HEADS][ECHUNK];
    __shared__ int   s_src[ECHUNK];

    const int beg = offsets[node];
    const int end = offsets[node + 1];

    const float2 xrv = *reinterpret_cast<const float2*>(&xr[(size_t)node * HC + h * HID + c0]);
    const float2 atv = *reinterpret_cast<const float2*>(&att[h * HID + c0]);

    float m = -INFINITY;
    float denom = 0.f;
    float2 acc = make_float2(0.f, 0.f);

    for (int cbeg = beg; cbeg < end; cbeg += ECHUNK) {
        const int cnt = min(ECHUNK, end - cbeg);
        for (int i = threadIdx.x; i < cnt; i += 256) s_src[i] = srcs[cbeg + i];
        __syncthreads();

        // pass 1: logits for this chunk
        for (int e = 0; e < cnt; ++e) {
            int s = s_src[e];
            float2 xlv = *reinterpret_cast<const float2*>(&xl[(size_t)s * HC + h * HID + c0]);
            float v0 = xlv.x + xrv.x; v0 = v0 > 0.f ? v0 : 0.2f * v0;
            float v1 = xlv.y + xrv.y; v1 = v1 > 0.f ? v1 : 0.2f * v1;
            float p = atv.x * v0 + atv.y * v1;
            #pragma unroll
            for (int off = 32; off; off >>= 1) p += __shfl_xor(p, off);
            if (lane == 0) s_logit[h][e] = p;
        }

        // chunk max (same wave wrote s_logit[h][*], wave-ordered)
        float cm = -INFINITY;
        for (int i = lane; i < cnt; i += 64) cm = fmaxf(cm, s_logit[h][i]);
        #pragma unroll
        for (int off = 32; off; off >>= 1) cm = fmaxf(cm, __shfl_xor(cm, off));

        float nm = fmaxf(m, cm);
        float scale = (m > -INFINITY) ? __expf(m - nm) : 0.f;
        denom *= scale; acc.x *= scale; acc.y *= scale;
        m = nm;

        // pass 2: p, denom, weighted aggregation
        for (int e = 0; e < cnt; ++e) {
            float p = __expf(s_logit[h][e] - m);
            int s = s_src[e];
            float2 xlv = *reinterpret_cast<const float2*>(&xl[(size_t)s * HC + h * HID + c0]);
            denom += p;
            acc.x += p * xlv.x;
            acc.y += p * xlv.y;
        }
        __syncthreads();
    }

    const float inv = 1.f / denom;    // deg >= 1 (self loop) always
    float2 bv = *reinterpret_cast<const float2*>(&bias[h * HID + c0]);
    float o0 = acc.x * inv + bv.x;
    float o1 = acc.y * inv + bv.y;
    o0 = o0 > 0.f ? o0 : expm1f(o0);
    o1 = o1 > 0.f ? o1 : expm1f(o1);
    *reinterpret_cast<float2*>(&hout[(size_t)node * HC + h * HID + c0]) = make_float2(o0, o1);
}

// ---------------------------------------------------------------------------
// Global mean pool (batch is sorted) + classifier, fused. One block per graph.
// ---------------------------------------------------------------------------
__global__ __launch_bounds__(256) void pool_cls_kernel(const float* __restrict__ h,
                                                       const int* __restrict__ batch,
                                                       const float* __restrict__ W,
                                                       const float* __restrict__ cb,
                                                       float* __restrict__ outp) {
    const int g = blockIdx.x;
    __shared__ float pooled[HC];

    int lo = 0, hi = NODES;
    while (lo < hi) { int mid = (lo + hi) >> 1; if (batch[mid] < g) lo = mid + 1; else hi = mid; }
    const int s = lo;
    lo = s; hi = NODES;
    while (lo < hi) { int mid = (lo + hi) >> 1; if (batch[mid] < g + 1) lo = mid + 1; else hi = mid; }
    const int e = lo;
    const int cnt = e - s;

    const int tid = threadIdx.x;
    const int c0 = tid * 2;
    float2 sum = make_float2(0.f, 0.f);
    for (int r = s; r < e; ++r) {
        float2 v = *reinterpret_cast<const float2*>(&h[(size_t)r * HC + c0]);
        sum.x += v.x; sum.y += v.y;
    }
    const float invc = cnt > 0 ? 1.f / (float)cnt : 0.f;
    pooled[c0] = sum.x * invc;
    pooled[c0 + 1] = sum.y * invc;
    __syncthreads();

    const int lane = tid & 63, wid = tid >> 6;
    for (int o = wid; o < OUT_F; o += 4) {
        float p = 0.f;
        for (int c = lane; c < HC; c += 64) p += pooled[c] * W[c * OUT_F + o];
        #pragma unroll
        for (int off = 32; off; off >>= 1) p += __shfl_xor(p, off);
        if (lane == 0) outp[g * OUT_F + o] = p + cb[o];
    }
}

// ---------------------------------------------------------------------------
// Host-side launch
// ---------------------------------------------------------------------------
extern "C" void kernel_launch(void* const* d_in, const int* in_sizes, int n_in,
                              void* d_out, int out_size, void* d_ws, size_t ws_size,
                              hipStream_t stream) {
    const float* x      = (const float*)d_in[0];
    const int*   ei     = (const int*)d_in[1];
    const int*   batch  = (const int*)d_in[2];
    const float* pre_W  = (const float*)d_in[3];
    const float* pre_b  = (const float*)d_in[4];
    const float* cls_W  = (const float*)d_in[5];
    const float* cls_b  = (const float*)d_in[6];
    // per-layer params start at 7, stride 6: Wl, bl, Wr, br, att, bias
    const float* Wl[3]; const float* bl[3]; const float* Wr[3];
    const float* br[3]; const float* attw[3]; const float* bw[3];
    for (int l = 0; l < 3; ++l) {
        Wl[l]   = (const float*)d_in[7 + 6 * l + 0];
        bl[l]   = (const float*)d_in[7 + 6 * l + 1];
        Wr[l]   = (const float*)d_in[7 + 6 * l + 2];
        br[l]   = (const float*)d_in[7 + 6 * l + 3];
        attw[l] = (const float*)d_in[7 + 6 * l + 4];
        bw[l]   = (const float*)d_in[7 + 6 * l + 5];
    }
    float* outp = (float*)d_out;

    // workspace carve
    float* hbuf = (float*)d_ws;                          // [NODES, HC] (pre uses [NODES, HID] prefix)
    float* xlb  = hbuf + (size_t)NODES * HC;             // [NODES, HC]
    float* xrb  = xlb + (size_t)NODES * HC;              // [NODES, HC]
    int* counts  = (int*)(xrb + (size_t)NODES * HC);     // [NODES]
    int* offsets = counts + NODES;                       // [NODES+1]
    int* cursor  = offsets + NODES + 1;                  // [NODES]
    int* srcs    = cursor + NODES;                       // [EPRIME]

    // --- edge sort (counting sort by dst) ---
    hipMemsetAsync(counts, 0, NODES * sizeof(int), stream);
    hist_kernel<<<(EPRIME + 255) / 256, 256, 0, stream>>>(ei, counts);
    scan_kernel<<<1, 1024, 0, stream>>>(counts, offsets, cursor);
    scatter_kernel<<<(EPRIME + 255) / 256, 256, 0, stream>>>(ei, cursor, srcs);

    const int mtiles = (NODES + BM - 1) / BM;

    // --- pre layer: h = elu(x @ pre_W + pre_b)  [NODES, HID] ---
    {
        dim3 grid(mtiles, HID / BN);
        gemm_bias<1><<<grid, 256, 0, stream>>>(x, pre_W, pre_b, hbuf, NODES, HID, IN_F);
    }

    // --- three GATv2 layers ---
    for (int l = 0; l < 3; ++l) {
        const int K = (l == 0) ? HID : HC;
        dim3 grid(mtiles, HC / BN);
        gemm_bias<0><<<grid, 256, 0, stream>>>(hbuf, Wl[l], bl[l], xlb, NODES, HC, K);
        gemm_bias<0><<<grid, 256, 0, stream>>>(hbuf, Wr[l], br[l], xrb, NODES, HC, K);
        gat_edge_kernel<<<NODES, 256, 0, stream>>>(xlb, xrb, attw[l], bw[l], offsets, srcs, hbuf);
    }

    // --- pool + classifier ---
    pool_cls_kernel<<<NGRAPH, 256, 0, stream>>>(hbuf, batch, cls_W, cls_b, outp);
}

// Round 2
// 954.964 us; speedup vs baseline: 1.6912x; 1.6912x over previous
//
#include <hip/hip_runtime.h>
#include <hip/hip_bf16.h>
#include <math.h>

// N=20000, IN_F=256, HID=128, HEADS=4, OUT_F=10, E=400000, G=64, HC=512
#define NODES   20000
#define MPAD    20096            // 157 * 128 (GEMM M padding)
#define IN_F    256
#define HID     128
#define HEADS   4
#define OUT_F   10
#define NEDGE   400000
#define NGRAPH  64
#define HC      512
#define EPRIME  (NEDGE + NODES)  // with self loops

typedef __attribute__((ext_vector_type(8))) short bf16x8_t;
typedef __attribute__((ext_vector_type(4))) float f32x4_t;

// ---- split-bf16 helpers: f32 x ~= hi + lo (each bf16), err ~2^-17 ----------
__device__ __forceinline__ unsigned short bf16_rne(float f) {
    unsigned int u = __float_as_uint(f);
    u += 0x7FFFu + ((u >> 16) & 1u);
    return (unsigned short)(u >> 16);
}
__device__ __forceinline__ float bf16f(unsigned short h) {
    return __uint_as_float(((unsigned int)h) << 16);
}
__device__ __forceinline__ void split2(float f, unsigned short& hi, unsigned short& lo) {
    hi = bf16_rne(f);
    lo = bf16_rne(f - bf16f(hi));
}

#define GLOAD_LDS16(gp, lp) \
    __builtin_amdgcn_global_load_lds((const __attribute__((address_space(1))) unsigned int*)(gp), \
                                     (__attribute__((address_space(3))) unsigned int*)(lp), 16, 0, 0)

// ---------------------------------------------------------------------------
// Edge preprocessing: counting sort by dst  (unchanged from round 0)
// ---------------------------------------------------------------------------
__global__ __launch_bounds__(256) void hist_kernel(const int* __restrict__ ei,
                                                   int* __restrict__ counts) {
    int e = blockIdx.x * blockDim.x + threadIdx.x;
    if (e >= EPRIME) return;
    int dst = (e < NEDGE) ? ei[NEDGE + e] : (e - NEDGE);
    atomicAdd(&counts[dst], 1);
}

__global__ __launch_bounds__(1024) void scan_kernel(const int* __restrict__ counts,
                                                    int* __restrict__ offsets,
                                                    int* __restrict__ cursor) {
    __shared__ int wsum[16];
    __shared__ int s_carry;
    const int tid = threadIdx.x;
    const int lane = tid & 63, wid = tid >> 6;
    if (tid == 0) s_carry = 0;
    __syncthreads();
    for (int base = 0; base < NODES; base += 1024) {
        int idx = base + tid;
        int v = (idx < NODES) ? counts[idx] : 0;
        int x = v;
        #pragma unroll
        for (int d = 1; d < 64; d <<= 1) {
            int n = __shfl_up(x, d);
            if (lane >= d) x += n;
        }
        if (lane == 63) wsum[wid] = x;
        __syncthreads();
        if (wid == 0) {
            int w = (lane < 16) ? wsum[lane] : 0;
            #pragma unroll
            for (int d = 1; d < 16; d <<= 1) {
                int n = __shfl_up(w, d);
                if (lane >= d) w += n;
            }
            if (lane < 16) wsum[lane] = w;
        }
        __syncthreads();
        int carry = s_carry;
        int wpre = (wid == 0) ? 0 : wsum[wid - 1];
        int excl = carry + wpre + x - v;
        if (idx < NODES) { offsets[idx] = excl; cursor[idx] = excl; }
        __syncthreads();
        if (tid == 1023) s_carry = carry + wsum[15];
        __syncthreads();
    }
    if (tid == 0) offsets[NODES] = s_carry;
}

__global__ __launch_bounds__(256) void scatter_kernel(const int* __restrict__ ei,
                                                      int* __restrict__ cursor,
                                                      int* __restrict__ srcs) {
    int e = blockIdx.x * blockDim.x + threadIdx.x;
    if (e >= EPRIME) return;
    int src, dst;
    if (e < NEDGE) { src = ei[e]; dst = ei[NEDGE + e]; }
    else           { src = dst = e - NEDGE; }
    int pos = atomicAdd(&cursor[dst], 1);
    srcs[pos] = src;
}

// ---------------------------------------------------------------------------
// Converters: f32 -> split-bf16 interleaved rows.
// Row layout for K logical cols: 4*K bytes; logical k = 8g+j:
//   hi short at byte g*32 + 2j ; lo short at byte g*32 + 16 + 2j
// ---------------------------------------------------------------------------
__global__ __launch_bounds__(256) void convert_x_kernel(const float* __restrict__ x,
                                                        unsigned short* __restrict__ x2) {
    int idx = blockIdx.x * 256 + threadIdx.x;     // (row, g) with g in [0, IN_F/8)
    int r = idx >> 5, g = idx & 31;
    if (r >= MPAD) return;
    __align__(16) unsigned short hv[8], lv[8];
    if (r < NODES) {
        const float* p = &x[(size_t)r * IN_F + g * 8];
        #pragma unroll
        for (int j = 0; j < 8; ++j) split2(p[j], hv[j], lv[j]);
    } else {
        #pragma unroll
        for (int j = 0; j < 8; ++j) { hv[j] = 0; lv[j] = 0; }
    }
    unsigned short* o = x2 + (size_t)r * (2 * IN_F) + g * 16;
    *reinterpret_cast<uint4*>(o)     = *reinterpret_cast<uint4*>(hv);
    *reinterpret_cast<uint4*>(o + 8) = *reinterpret_cast<uint4*>(lv);
}

// W [K][N] f32 -> WT2 [N][4*K bytes] split-interleaved (i.e. B^T, MFMA-ready)
__global__ __launch_bounds__(256) void convert_w_kernel(const float* __restrict__ W,
                                                        unsigned short* __restrict__ WT2,
                                                        int K, int N, int gshift) {
    int idx = blockIdx.x * 256 + threadIdx.x;
    int n = idx >> gshift, g = idx & ((1 << gshift) - 1);
    if (n >= N) return;
    __align__(16) unsigned short hv[8], lv[8];
    #pragma unroll
    for (int j = 0; j < 8; ++j) split2(W[(size_t)(8 * g + j) * N + n], hv[j], lv[j]);
    unsigned short* o = WT2 + (size_t)n * (2 * K) + g * 16;
    *reinterpret_cast<uint4*>(o)     = *reinterpret_cast<uint4*>(hv);
    *reinterpret_cast<uint4*>(o + 8) = *reinterpret_cast<uint4*>(lv);
}

// ---------------------------------------------------------------------------
// Split-bf16 MFMA GEMM: C[M,N] = split(A) @ split(B^T)^T + bias
// 128x128 tile, 4 waves (2x2, each 64x64 = 4x4 frags of 16x16),
// BK=32 logical (128B interleaved per row), global_load_lds width 16 with
// pre-swizzled source (XOR (row&7)<<4) -> conflict-free ds_read_b128.
// 3 MFMAs per fragment pair: hi*hi + hi*lo + lo*hi.
// ---------------------------------------------------------------------------
template <int WRITE_SPLIT, int ACT>
__global__ __launch_bounds__(256) void mfma_gemm_kernel(const unsigned short* __restrict__ A2,
                                                        const unsigned short* __restrict__ B2,
                                                        const float* __restrict__ bias,
                                                        float* __restrict__ Cf,
                                                        unsigned short* __restrict__ C2,
                                                        int M, int N, int K) {
    __shared__ char lds[32768];        // [0,16K) A-tile, [16K,32K) B-tile
    const int tid = threadIdx.x;
    const int w = tid >> 6, l = tid & 63;
    const int wr = w >> 1, wc = w & 1;
    const int row0 = blockIdx.x * 128, col0 = blockIdx.y * 128;
    const size_t rowB = (size_t)K * 4;  // bytes per split row

    f32x4_t acc[4][4];
    #pragma unroll
    for (int i = 0; i < 4; ++i)
        #pragma unroll
        for (int j = 0; j < 4; ++j)
            #pragma unroll
            for (int q = 0; q < 4; ++q) acc[i][j][q] = 0.f;

    const int ssub = l >> 3;           // staging row-within-instr 0..7
    const int scol = (l & 7) * 16;     // staging byte col
    const int g16  = l >> 4;           // MFMA k-octet group
    const int fr   = l & 15;

    const char* Ab = (const char*)A2;
    const char* Bb = (const char*)B2;

    const int nsteps = K >> 5;
    for (int t = 0; t < nsteps; ++t) {
        #pragma unroll
        for (int i = 0; i < 4; ++i) {  // A: rows w*32+i*8 .. +7
            int r = w * 32 + i * 8 + ssub;
            size_t gb = (size_t)(row0 + r) * rowB + (size_t)t * 128 + (size_t)(scol ^ ((r & 7) << 4));
            GLOAD_LDS16(Ab + gb, &lds[(w * 32 + i * 8) * 128]);
        }
        #pragma unroll
        for (int i = 0; i < 4; ++i) {  // B: "rows" are output cols
            int r = w * 32 + i * 8 + ssub;
            size_t gb = (size_t)(col0 + r) * rowB + (size_t)t * 128 + (size_t)(scol ^ ((r & 7) << 4));
            GLOAD_LDS16(Bb + gb, &lds[16384 + (w * 32 + i * 8) * 128]);
        }
        asm volatile("s_waitcnt vmcnt(0)" ::: "memory");
        __syncthreads();

        bf16x8_t ah[4], al[4];
        #pragma unroll
        for (int i = 0; i < 4; ++i) {
            int r = wr * 64 + i * 16 + fr;
            int sw = (r & 7) << 4;
            ah[i] = *reinterpret_cast<const bf16x8_t*>(&lds[r * 128 + ((g16 * 32) ^ sw)]);
            al[i] = *reinterpret_cast<const bf16x8_t*>(&lds[r * 128 + ((g16 * 32 + 16) ^ sw)]);
        }
        #pragma unroll
        for (int j = 0; j < 4; ++j) {
            int r = wc * 64 + j * 16 + fr;
            int sw = (r & 7) << 4;
            bf16x8_t bh = *reinterpret_cast<const bf16x8_t*>(&lds[16384 + r * 128 + ((g16 * 32) ^ sw)]);
            bf16x8_t bl = *reinterpret_cast<const bf16x8_t*>(&lds[16384 + r * 128 + ((g16 * 32 + 16) ^ sw)]);
            #pragma unroll
            for (int i = 0; i < 4; ++i) {
                acc[i][j] = __builtin_amdgcn_mfma_f32_16x16x32_bf16(ah[i], bh, acc[i][j], 0, 0, 0);
                acc[i][j] = __builtin_amdgcn_mfma_f32_16x16x32_bf16(ah[i], bl, acc[i][j], 0, 0, 0);
                acc[i][j] = __builtin_amdgcn_mfma_f32_16x16x32_bf16(al[i], bh, acc[i][j], 0, 0, 0);
            }
        }
        __syncthreads();
    }

    // epilogue: C/D frag mapping col = l&15, row = (l>>4)*4 + reg   [m89]
    const int crb  = (l >> 4) * 4;
    const int ccol = l & 15;
    #pragma unroll
    for (int i = 0; i < 4; ++i) {
        #pragma unroll
        for (int jj = 0; jj < 4; ++jj) {
            int rg = row0 + wr * 64 + i * 16 + crb + jj;
            #pragma unroll
            for (int j = 0; j < 4; ++j) {
                int cg = col0 + wc * 64 + j * 16 + ccol;
                float v = acc[i][j][jj] + bias[cg];
                if (ACT) v = v > 0.f ? v : expm1f(v);
                if (WRITE_SPLIT) {
                    unsigned short hi, lo;
                    split2(v, hi, lo);
                    unsigned short* o = C2 + (size_t)rg * (2 * N) + (cg >> 3) * 16 + (cg & 7);
                    o[0] = hi; o[8] = lo;
                } else {
                    if (rg < M) Cf[(size_t)rg * N + cg] = v;
                }
            }
        }
    }
}

// ---------------------------------------------------------------------------
// Fused GATv2 edge kernel, SINGLE-PASS online softmax (xl read once/edge).
// One block per node; wave = head; lane holds 2 channels. Output written as
// split-bf16 interleaved (feeds next GEMM / pool). Pad rows write zeros.
// ---------------------------------------------------------------------------
__global__ __launch_bounds__(256) void gat_edge_kernel(const float* __restrict__ xl,
                                                       const float* __restrict__ xr,
                                                       const float* __restrict__ att,
                                                       const float* __restrict__ bias,
                                                       const int* __restrict__ offsets,
                                                       const int* __restrict__ srcs,
                                                       unsigned short* __restrict__ h2) {
    const int node = blockIdx.x;
    if (node >= NODES) {   // zero the GEMM pad rows (ws is poisoned each call)
        uint2* o = (uint2*)(h2 + (size_t)node * (2 * HC));
        o[threadIdx.x] = make_uint2(0u, 0u);
        return;
    }
    const int h = threadIdx.x >> 6, lane = threadIdx.x & 63;
    const int c0 = lane * 2;
    const size_t xoff = (size_t)node * HC + h * HID + c0;
    const float2 xrv = *reinterpret_cast<const float2*>(&xr[xoff]);
    const float2 atv = *reinterpret_cast<const float2*>(&att[h * HID + c0]);
    const int beg = offsets[node], end = offsets[node + 1];

    float m = -INFINITY, denom = 0.f, a0 = 0.f, a1 = 0.f;

    for (int e0 = beg; e0 < end; e0 += 4) {
        int nb = end - e0; if (nb > 4) nb = 4;
        int sx[4]; float2 xv[4];
        #pragma unroll
        for (int q = 0; q < 4; ++q) sx[q] = srcs[e0 + ((q < nb) ? q : 0)];
        #pragma unroll
        for (int q = 0; q < 4; ++q)
            xv[q] = *reinterpret_cast<const float2*>(&xl[(size_t)sx[q] * HC + h * HID + c0]);
        #pragma unroll
        for (int q = 0; q < 4; ++q) {
            if (q >= nb) break;                       // wave-uniform
            float v0 = xv[q].x + xrv.x; v0 = fmaxf(v0, 0.2f * v0);   // leaky 0.2
            float v1 = xv[q].y + xrv.y; v1 = fmaxf(v1, 0.2f * v1);
            float p = atv.x * v0 + atv.y * v1;
            #pragma unroll
            for (int off = 32; off; off >>= 1) p += __shfl_xor(p, off);
            if (p > m) {                              // uniform rescale branch
                float sc = __expf(m - p);
                denom *= sc; a0 *= sc; a1 *= sc; m = p;
            }
            float wgt = __expf(p - m);
            denom += wgt; a0 += wgt * xv[q].x; a1 += wgt * xv[q].y;
        }
    }

    const float inv = 1.f / denom;                    // self-loop => denom>0
    const float2 bv = *reinterpret_cast<const float2*>(&bias[h * HID + c0]);
    float o0 = a0 * inv + bv.x, o1 = a1 * inv + bv.y;
    o0 = o0 > 0.f ? o0 : expm1f(o0);
    o1 = o1 > 0.f ? o1 : expm1f(o1);
    const int c = h * HID + c0;                       // even channel
    unsigned short h0, l0, h1, l1;
    split2(o0, h0, l0); split2(o1, h1, l1);
    unsigned short* o = h2 + (size_t)node * (2 * HC) + (c >> 3) * 16 + (c & 7);
    o[0] = h0; o[1] = h1; o[8] = l0; o[9] = l1;
}

// ---------------------------------------------------------------------------
// Global mean pool (sorted batch) + classifier. Reads split-bf16 h2.
// ---------------------------------------------------------------------------
__global__ __launch_bounds__(256) void pool_cls_kernel(const unsigned short* __restrict__ h2,
                                                       const int* __restrict__ batch,
                                                       const float* __restrict__ W,
                                                       const float* __restrict__ cb,
                                                       float* __restrict__ outp) {
    const int g = blockIdx.x;
    __shared__ float pooled[HC];
    int lo = 0, hi = NODES;
    while (lo < hi) { int mid = (lo + hi) >> 1; if (batch[mid] < g) lo = mid + 1; else hi = mid; }
    const int s = lo;
    lo = s; hi = NODES;
    while (lo < hi) { int mid = (lo + hi) >> 1; if (batch[mid] < g + 1) lo = mid + 1; else hi = mid; }
    const int e = lo;

    const int tid = threadIdx.x;
    const int c0 = tid * 2;
    const int boff = ((c0 >> 3) * 16) + (c0 & 7);
    float s0 = 0.f, s1 = 0.f;
    for (int r = s; r < e; ++r) {
        const unsigned short* p = h2 + (size_t)r * (2 * HC) + boff;
        s0 += bf16f(p[0]) + bf16f(p[8]);
        s1 += bf16f(p[1]) + bf16f(p[9]);
    }
    const float invc = (e > s) ? 1.f / (float)(e - s) : 0.f;
    pooled[c0] = s0 * invc; pooled[c0 + 1] = s1 * invc;
    __syncthreads();

    const int lane = tid & 63, wid = tid >> 6;
    for (int o = wid; o < OUT_F; o += 4) {
        float p = 0.f;
        for (int c = lane; c < HC; c += 64) p += pooled[c] * W[c * OUT_F + o];
        #pragma unroll
        for (int off2 = 32; off2; off2 >>= 1) p += __shfl_xor(p, off2);
        if (lane == 0) outp[g * OUT_F + o] = p + cb[o];
    }
}

// ---------------------------------------------------------------------------
// Host-side launch
// ---------------------------------------------------------------------------
extern "C" void kernel_launch(void* const* d_in, const int* in_sizes, int n_in,
                              void* d_out, int out_size, void* d_ws, size_t ws_size,
                              hipStream_t stream) {
    const float* x      = (const float*)d_in[0];
    const int*   ei     = (const int*)d_in[1];
    const int*   batch  = (const int*)d_in[2];
    const float* pre_W  = (const float*)d_in[3];
    const float* pre_b  = (const float*)d_in[4];
    const float* cls_W  = (const float*)d_in[5];
    const float* cls_b  = (const float*)d_in[6];
    const float* Wl[3]; const float* bl[3]; const float* Wr[3];
    const float* br[3]; const float* attw[3]; const float* bw[3];
    for (int l = 0; l < 3; ++l) {
        Wl[l]   = (const float*)d_in[7 + 6 * l + 0];
        bl[l]   = (const float*)d_in[7 + 6 * l + 1];
        Wr[l]   = (const float*)d_in[7 + 6 * l + 2];
        br[l]   = (const float*)d_in[7 + 6 * l + 3];
        attw[l] = (const float*)d_in[7 + 6 * l + 4];
        bw[l]   = (const float*)d_in[7 + 6 * l + 5];
    }
    float* outp = (float*)d_out;

    // ---- workspace carve (~127 MB, with lifetime-based aliasing) ----
    char* ws = (char*)d_ws;
    size_t off = 0;
    auto alloc = [&](size_t b) { char* p = ws + off; off += (b + 255) & ~(size_t)255; return p; };
    float* xlb = (float*)alloc((size_t)NODES * HC * 4);                 // 41.0 MB
    float* xrb = (float*)alloc((size_t)NODES * HC * 4);                 // 41.0 MB
    unsigned short* h2 = (unsigned short*)alloc((size_t)MPAD * 2 * HC * 2); // 41.2 MB
    unsigned short* WlT2 = (unsigned short*)alloc((size_t)HC * 2 * HC * 2); // 1 MB (reused/layer)
    unsigned short* WrT2 = (unsigned short*)alloc((size_t)HC * 2 * HC * 2); // 1 MB
    unsigned short* preWT2 = (unsigned short*)alloc((size_t)HID * 2 * IN_F * 2); // 128 KB
    int* counts  = (int*)alloc(NODES * 4);
    int* offsets = (int*)alloc((NODES + 1) * 4);
    int* cursor  = (int*)alloc(NODES * 4);
    int* srcs    = (int*)alloc((size_t)EPRIME * 4);
    // aliases (disjoint lifetimes):
    unsigned short* x2  = (unsigned short*)xlb;  // [MPAD][2*IN_F] dead before xlb written
    unsigned short* h2a = h2;                    // [MPAD][2*HID]  dead before h2 written

    // ---- edge sort ----
    hipMemsetAsync(counts, 0, NODES * 4, stream);
    hist_kernel<<<(EPRIME + 255) / 256, 256, 0, stream>>>(ei, counts);
    scan_kernel<<<1, 1024, 0, stream>>>(counts, offsets, cursor);
    scatter_kernel<<<(EPRIME + 255) / 256, 256, 0, stream>>>(ei, cursor, srcs);

    // ---- input / weight conversion ----
    convert_x_kernel<<<(MPAD * (IN_F / 8) + 255) / 256, 256, 0, stream>>>(x, x2);
    convert_w_kernel<<<(HID * (IN_F / 8) + 255) / 256, 256, 0, stream>>>(pre_W, preWT2, IN_F, HID, 5);
    convert_w_kernel<<<(HC * (HID / 8) + 255) / 256, 256, 0, stream>>>(Wl[0], WlT2, HID, HC, 4);
    convert_w_kernel<<<(HC * (HID / 8) + 255) / 256, 256, 0, stream>>>(Wr[0], WrT2, HID, HC, 4);

    // ---- pre layer: h = elu(x @ pre_W + pre_b), split-written ----
    mfma_gemm_kernel<1, 1><<<dim3(157, 1), 256, 0, stream>>>(x2, preWT2, pre_b,
                                                             nullptr, h2a, NODES, HID, IN_F);

    // ---- layer 1 ----
    mfma_gemm_kernel<0, 0><<<dim3(157, 4), 256, 0, stream>>>(h2a, WlT2, bl[0], xlb, nullptr, NODES, HC, HID);
    mfma_gemm_kernel<0, 0><<<dim3(157, 4), 256, 0, stream>>>(h2a, WrT2, br[0], xrb, nullptr, NODES, HC, HID);
    convert_w_kernel<<<(HC * (HC / 8) + 255) / 256, 256, 0, stream>>>(Wl[1], WlT2, HC, HC, 6);
    convert_w_kernel<<<(HC * (HC / 8) + 255) / 256, 256, 0, stream>>>(Wr[1], WrT2, HC, HC, 6);
    gat_edge_kernel<<<MPAD, 256, 0, stream>>>(xlb, xrb, attw[0], bw[0], offsets, srcs, h2);

    // ---- layer 2 ----
    mfma_gemm_kernel<0, 0><<<dim3(157, 4), 256, 0, stream>>>(h2, WlT2, bl[1], xlb, nullptr, NODES, HC, HC);
    mfma_gemm_kernel<0, 0><<<dim3(157, 4), 256, 0, stream>>>(h2, WrT2, br[1], xrb, nullptr, NODES, HC, HC);
    convert_w_kernel<<<(HC * (HC / 8) + 255) / 256, 256, 0, stream>>>(Wl[2], WlT2, HC, HC, 6);
    convert_w_kernel<<<(HC * (HC / 8) + 255) / 256, 256, 0, stream>>>(Wr[2], WrT2, HC, HC, 6);
    gat_edge_kernel<<<MPAD, 256, 0, stream>>>(xlb, xrb, attw[1], bw[1], offsets, srcs, h2);

    // ---- layer 3 ----
    mfma_gemm_kernel<0, 0><<<dim3(157, 4), 256, 0, stream>>>(h2, WlT2, bl[2], xlb, nullptr, NODES, HC, HC);
    mfma_gemm_kernel<0, 0><<<dim3(157, 4), 256, 0, stream>>>(h2, WrT2, br[2], xrb, nullptr, NODES, HC, HC);
    gat_edge_kernel<<<MPAD, 256, 0, stream>>>(xlb, xrb, attw[2], bw[2], offsets, srcs, h2);

    // ---- pool + classifier ----
    pool_cls_kernel<<<NGRAPH, 256, 0, stream>>>(h2, batch, cls_W, cls_b, outp);
}

// Round 3
// 826.126 us; speedup vs baseline: 1.9549x; 1.1560x over previous
//
#include <hip/hip_runtime.h>
#include <hip/hip_bf16.h>
#include <math.h>

// N=20000, IN_F=256, HID=128, HEADS=4, OUT_F=10, E=400000, G=64, HC=512
#define NODES   20000
#define MPAD    20096            // 157 * 128 (GEMM M padding)
#define IN_F    256
#define HID     128
#define HEADS   4
#define OUT_F   10
#define NEDGE   400000
#define NGRAPH  64
#define HC      512
#define EPRIME  (NEDGE + NODES)  // with self loops
#define XLRW    1024             // fused [xl|xr] row width (floats)

typedef __attribute__((ext_vector_type(8))) short bf16x8_t;
typedef __attribute__((ext_vector_type(4))) float f32x4_t;

// ---- split-bf16 helpers: f32 x ~= hi + lo (each bf16), err ~2^-18 ----------
__device__ __forceinline__ unsigned short bf16_rne(float f) {
    unsigned int u = __float_as_uint(f);
    u += 0x7FFFu + ((u >> 16) & 1u);
    return (unsigned short)(u >> 16);
}
__device__ __forceinline__ float bf16f(unsigned short h) {
    return __uint_as_float(((unsigned int)h) << 16);
}
__device__ __forceinline__ void split2(float f, unsigned short& hi, unsigned short& lo) {
    hi = bf16_rne(f);
    lo = bf16_rne(f - bf16f(hi));
}

#define GLOAD_LDS16(gp, lp) \
    __builtin_amdgcn_global_load_lds((const __attribute__((address_space(1))) unsigned int*)(gp), \
                                     (__attribute__((address_space(3))) unsigned int*)(lp), 16, 0, 0)

// ---------------------------------------------------------------------------
// Edge preprocessing: counting sort by dst; srcs stored pre-scaled to byte
// offsets of the fused xlr row (src * 4096).
// ---------------------------------------------------------------------------
__global__ __launch_bounds__(256) void hist_kernel(const int* __restrict__ ei,
                                                   int* __restrict__ counts) {
    int e = blockIdx.x * blockDim.x + threadIdx.x;
    if (e >= EPRIME) return;
    int dst = (e < NEDGE) ? ei[NEDGE + e] : (e - NEDGE);
    atomicAdd(&counts[dst], 1);
}

__global__ __launch_bounds__(1024) void scan_kernel(const int* __restrict__ counts,
                                                    int* __restrict__ offsets,
                                                    int* __restrict__ cursor) {
    __shared__ int wsum[16];
    __shared__ int s_carry;
    const int tid = threadIdx.x;
    const int lane = tid & 63, wid = tid >> 6;
    if (tid == 0) s_carry = 0;
    __syncthreads();
    for (int base = 0; base < NODES; base += 1024) {
        int idx = base + tid;
        int v = (idx < NODES) ? counts[idx] : 0;
        int x = v;
        #pragma unroll
        for (int d = 1; d < 64; d <<= 1) {
            int n = __shfl_up(x, d);
            if (lane >= d) x += n;
        }
        if (lane == 63) wsum[wid] = x;
        __syncthreads();
        if (wid == 0) {
            int w = (lane < 16) ? wsum[lane] : 0;
            #pragma unroll
            for (int d = 1; d < 16; d <<= 1) {
                int n = __shfl_up(w, d);
                if (lane >= d) w += n;
            }
            if (lane < 16) wsum[lane] = w;
        }
        __syncthreads();
        int carry = s_carry;
        int wpre = (wid == 0) ? 0 : wsum[wid - 1];
        int excl = carry + wpre + x - v;
        if (idx < NODES) { offsets[idx] = excl; cursor[idx] = excl; }
        __syncthreads();
        if (tid == 1023) s_carry = carry + wsum[15];
        __syncthreads();
    }
    if (tid == 0) offsets[NODES] = s_carry;
}

__global__ __launch_bounds__(256) void scatter_kernel(const int* __restrict__ ei,
                                                      int* __restrict__ cursor,
                                                      int* __restrict__ srcsb) {
    int e = blockIdx.x * blockDim.x + threadIdx.x;
    if (e >= EPRIME) return;
    int src, dst;
    if (e < NEDGE) { src = ei[e]; dst = ei[NEDGE + e]; }
    else           { src = dst = e - NEDGE; }
    int pos = atomicAdd(&cursor[dst], 1);
    srcsb[pos] = src << 12;            // byte offset: src * XLRW * 4
}

// ---------------------------------------------------------------------------
// Converters: f32 -> split-bf16 interleaved rows.
// Row layout for K logical cols: 4*K bytes; logical k = 8g+j:
//   hi short at byte g*32 + 2j ; lo short at byte g*32 + 16 + 2j
// ---------------------------------------------------------------------------
__global__ __launch_bounds__(256) void convert_x_kernel(const float* __restrict__ x,
                                                        unsigned short* __restrict__ x2) {
    int idx = blockIdx.x * 256 + threadIdx.x;     // (row, g) with g in [0, IN_F/8)
    int r = idx >> 5, g = idx & 31;
    if (r >= MPAD) return;
    __align__(16) unsigned short hv[8], lv[8];
    if (r < NODES) {
        const float* p = &x[(size_t)r * IN_F + g * 8];
        #pragma unroll
        for (int j = 0; j < 8; ++j) split2(p[j], hv[j], lv[j]);
    } else {
        #pragma unroll
        for (int j = 0; j < 8; ++j) { hv[j] = 0; lv[j] = 0; }
    }
    unsigned short* o = x2 + (size_t)r * (2 * IN_F) + g * 16;
    *reinterpret_cast<uint4*>(o)     = *reinterpret_cast<uint4*>(hv);
    *reinterpret_cast<uint4*>(o + 8) = *reinterpret_cast<uint4*>(lv);
}

// W [K][N] f32 -> WT2 [N][4*K bytes] split-interleaved (i.e. B^T, MFMA-ready)
__global__ __launch_bounds__(256) void convert_w_kernel(const float* __restrict__ W,
                                                        unsigned short* __restrict__ WT2,
                                                        int K, int N, int gshift) {
    int idx = blockIdx.x * 256 + threadIdx.x;
    int n = idx >> gshift, g = idx & ((1 << gshift) - 1);
    if (n >= N) return;
    __align__(16) unsigned short hv[8], lv[8];
    #pragma unroll
    for (int j = 0; j < 8; ++j) split2(W[(size_t)(8 * g + j) * N + n], hv[j], lv[j]);
    unsigned short* o = WT2 + (size_t)n * (2 * K) + g * 16;
    *reinterpret_cast<uint4*>(o)     = *reinterpret_cast<uint4*>(hv);
    *reinterpret_cast<uint4*>(o + 8) = *reinterpret_cast<uint4*>(lv);
}

// concat [bl|br] per layer -> biascat[3][1024]
__global__ __launch_bounds__(256) void build_bias_kernel(const float* __restrict__ bl1,
                                                         const float* __restrict__ br1,
                                                         const float* __restrict__ bl2,
                                                         const float* __restrict__ br2,
                                                         const float* __restrict__ bl3,
                                                         const float* __restrict__ br3,
                                                         float* __restrict__ out) {
    int idx = blockIdx.x * 256 + threadIdx.x;
    if (idx >= 3 * 1024) return;
    int l = idx >> 10, c = idx & 1023;
    const float* p = (l == 0) ? (c < 512 ? bl1 : br1)
                   : (l == 1) ? (c < 512 ? bl2 : br2)
                              : (c < 512 ? bl3 : br3);
    out[idx] = p[c & 511];
}

// ---------------------------------------------------------------------------
// Split-bf16 MFMA GEMM: C[M,N] = split(A) @ split(B^T)^T + bias
// 128x128 tile, 4 waves (2x2, each 64x64 = 4x4 frags of 16x16),
// BK=32 logical (128B interleaved per row), global_load_lds width 16 with
// pre-swizzled source (XOR (row&7)<<4) -> conflict-free ds_read_b128.
// 3 MFMAs per fragment pair: hi*hi + hi*lo + lo*hi.
// ---------------------------------------------------------------------------
template <int WRITE_SPLIT, int ACT>
__global__ __launch_bounds__(256) void mfma_gemm_kernel(const unsigned short* __restrict__ A2,
                                                        const unsigned short* __restrict__ B2,
                                                        const float* __restrict__ bias,
                                                        float* __restrict__ Cf,
                                                        unsigned short* __restrict__ C2,
                                                        int M, int N, int K) {
    __shared__ char lds[32768];        // [0,16K) A-tile, [16K,32K) B-tile
    const int tid = threadIdx.x;
    const int w = tid >> 6, l = tid & 63;
    const int wr = w >> 1, wc = w & 1;
    const int row0 = blockIdx.x * 128, col0 = blockIdx.y * 128;
    const size_t rowB = (size_t)K * 4;  // bytes per split row

    f32x4_t acc[4][4];
    #pragma unroll
    for (int i = 0; i < 4; ++i)
        #pragma unroll
        for (int j = 0; j < 4; ++j)
            #pragma unroll
            for (int q = 0; q < 4; ++q) acc[i][j][q] = 0.f;

    const int ssub = l >> 3;           // staging row-within-instr 0..7
    const int scol = (l & 7) * 16;     // staging byte col
    const int g16  = l >> 4;           // MFMA k-octet group
    const int fr   = l & 15;

    const char* Ab = (const char*)A2;
    const char* Bb = (const char*)B2;

    const int nsteps = K >> 5;
    for (int t = 0; t < nsteps; ++t) {
        #pragma unroll
        for (int i = 0; i < 4; ++i) {  // A: rows w*32+i*8 .. +7
            int r = w * 32 + i * 8 + ssub;
            size_t gb = (size_t)(row0 + r) * rowB + (size_t)t * 128 + (size_t)(scol ^ ((r & 7) << 4));
            GLOAD_LDS16(Ab + gb, &lds[(w * 32 + i * 8) * 128]);
        }
        #pragma unroll
        for (int i = 0; i < 4; ++i) {  // B: "rows" are output cols
            int r = w * 32 + i * 8 + ssub;
            size_t gb = (size_t)(col0 + r) * rowB + (size_t)t * 128 + (size_t)(scol ^ ((r & 7) << 4));
            GLOAD_LDS16(Bb + gb, &lds[16384 + (w * 32 + i * 8) * 128]);
        }
        asm volatile("s_waitcnt vmcnt(0)" ::: "memory");
        __syncthreads();

        bf16x8_t ah[4], al[4];
        #pragma unroll
        for (int i = 0; i < 4; ++i) {
            int r = wr * 64 + i * 16 + fr;
            int sw = (r & 7) << 4;
            ah[i] = *reinterpret_cast<const bf16x8_t*>(&lds[r * 128 + ((g16 * 32) ^ sw)]);
            al[i] = *reinterpret_cast<const bf16x8_t*>(&lds[r * 128 + ((g16 * 32 + 16) ^ sw)]);
        }
        #pragma unroll
        for (int j = 0; j < 4; ++j) {
            int r = wc * 64 + j * 16 + fr;
            int sw = (r & 7) << 4;
            bf16x8_t bh = *reinterpret_cast<const bf16x8_t*>(&lds[16384 + r * 128 + ((g16 * 32) ^ sw)]);
            bf16x8_t bl = *reinterpret_cast<const bf16x8_t*>(&lds[16384 + r * 128 + ((g16 * 32 + 16) ^ sw)]);
            #pragma unroll
            for (int i = 0; i < 4; ++i) {
                acc[i][j] = __builtin_amdgcn_mfma_f32_16x16x32_bf16(ah[i], bh, acc[i][j], 0, 0, 0);
                acc[i][j] = __builtin_amdgcn_mfma_f32_16x16x32_bf16(ah[i], bl, acc[i][j], 0, 0, 0);
                acc[i][j] = __builtin_amdgcn_mfma_f32_16x16x32_bf16(al[i], bh, acc[i][j], 0, 0, 0);
            }
        }
        __syncthreads();
    }

    // epilogue: C/D frag mapping col = l&15, row = (l>>4)*4 + reg   [m89]
    const int crb  = (l >> 4) * 4;
    const int ccol = l & 15;
    #pragma unroll
    for (int i = 0; i < 4; ++i) {
        #pragma unroll
        for (int jj = 0; jj < 4; ++jj) {
            int rg = row0 + wr * 64 + i * 16 + crb + jj;
            #pragma unroll
            for (int j = 0; j < 4; ++j) {
                int cg = col0 + wc * 64 + j * 16 + ccol;
                float v = acc[i][j][jj] + bias[cg];
                if (ACT) v = v > 0.f ? v : expm1f(v);
                if (WRITE_SPLIT) {
                    unsigned short hi, lo;
                    split2(v, hi, lo);
                    unsigned short* o = C2 + (size_t)rg * (2 * N) + (cg >> 3) * 16 + (cg & 7);
                    o[0] = hi; o[8] = lo;
                } else {
                    if (rg < M) Cf[(size_t)rg * N + cg] = v;
                }
            }
        }
    }
}

// ---------------------------------------------------------------------------
// Fused GATv2 edge kernel, single-pass online softmax, 4-edge batches with
// fold-reduce (select-before-shfl) for the logit reduction. exp in base-2
// domain (att pre-scaled by log2e). xlr rows are [xl(512) | xr(512)] f32.
// ---------------------------------------------------------------------------
__global__ __launch_bounds__(256) void gat_edge_kernel(const float* __restrict__ xlr,
                                                       const float* __restrict__ att,
                                                       const float* __restrict__ bias,
                                                       const int* __restrict__ offsets,
                                                       const int* __restrict__ srcsb,
                                                       unsigned short* __restrict__ h2) {
    const int node = blockIdx.x;
    if (node >= NODES) {   // zero the GEMM pad rows (ws is poisoned each call)
        uint2* o = (uint2*)(h2 + (size_t)node * (2 * HC));
        o[threadIdx.x] = make_uint2(0u, 0u);
        return;
    }
    const int h = threadIdx.x >> 6, lane = threadIdx.x & 63;
    const int c0 = lane * 2;
    const int ch = h * HID + c0;                  // 0..511
    const char* xlb = (const char*)xlr;
    const int laneoff = ch * 4;                   // byte offset inside xl part
    const float2 xrv = *reinterpret_cast<const float2*>(&xlr[(size_t)node * XLRW + 512 + ch]);
    float2 atv = *reinterpret_cast<const float2*>(&att[ch]);
    atv.x *= 1.44269504f; atv.y *= 1.44269504f;   // log2(e): exp -> exp2
    const int beg = offsets[node], end = offsets[node + 1];

    float m = -INFINITY, denom = 0.f, a0 = 0.f, a1 = 0.f;
    const bool b5 = (lane & 32) != 0, b4 = (lane & 16) != 0;

    for (int e0 = beg; e0 < end; e0 += 4) {
        const int nb = min(4, end - e0);          // >=1 (self loop)
        int sb[4]; float2 xv[4]; float p[4];
        #pragma unroll
        for (int q = 0; q < 4; ++q) sb[q] = srcsb[e0 + ((q < nb) ? q : nb - 1)];
        #pragma unroll
        for (int q = 0; q < 4; ++q)
            xv[q] = *reinterpret_cast<const float2*>(xlb + (size_t)(unsigned)sb[q] + laneoff);
        #pragma unroll
        for (int q = 0; q < 4; ++q) {
            float v0 = xv[q].x + xrv.x; v0 = fmaxf(v0, 0.2f * v0);   // leaky 0.2
            float v1 = xv[q].y + xrv.y; v1 = fmaxf(v1, 0.2f * v1);
            p[q] = fmaf(atv.y, v1, atv.x * v0);
        }
        // fold-reduce: 4 sums over 64 lanes in 3 shfl + 4-stage butterfly
        float s0 = b5 ? p[0] : p[2];
        float u0 = (b5 ? p[2] : p[0]) + __shfl_xor(s0, 32);
        float s1 = b5 ? p[1] : p[3];
        float u1 = (b5 ? p[3] : p[1]) + __shfl_xor(s1, 32);
        float s2 = b4 ? u0 : u1;
        float t  = (b4 ? u1 : u0) + __shfl_xor(s2, 16);
        t += __shfl_xor(t, 8);
        t += __shfl_xor(t, 4);
        t += __shfl_xor(t, 2);
        t += __shfl_xor(t, 1);
        // value e=2*b5+b4 fully summed in lane group e*16..e*16+15
        const float pe0 = __shfl(t, 0);
        const float pe1 = __shfl(t, 16);
        const float pe2 = __shfl(t, 32);
        const float pe3 = __shfl(t, 48);

        const float m4 = fmaxf(fmaxf(pe0, pe1), fmaxf(pe2, pe3));  // dups of last valid edge: harmless
        if (m4 > m) {
            float sc = exp2f(m - m4);
            denom *= sc; a0 *= sc; a1 *= sc; m = m4;
        }
        {
            float w0 = exp2f(pe0 - m);
            denom += w0; a0 = fmaf(w0, xv[0].x, a0); a1 = fmaf(w0, xv[0].y, a1);
        }
        if (nb > 1) {
            float w1 = exp2f(pe1 - m);
            denom += w1; a0 = fmaf(w1, xv[1].x, a0); a1 = fmaf(w1, xv[1].y, a1);
        }
        if (nb > 2) {
            float w2 = exp2f(pe2 - m);
            denom += w2; a0 = fmaf(w2, xv[2].x, a0); a1 = fmaf(w2, xv[2].y, a1);
        }
        if (nb > 3) {
            float w3 = exp2f(pe3 - m);
            denom += w3; a0 = fmaf(w3, xv[3].x, a0); a1 = fmaf(w3, xv[3].y, a1);
        }
    }

    const float inv = 1.f / denom;
    const float2 bv = *reinterpret_cast<const float2*>(&bias[ch]);
    float o0 = a0 * inv + bv.x, o1 = a1 * inv + bv.y;
    o0 = o0 > 0.f ? o0 : expm1f(o0);
    o1 = o1 > 0.f ? o1 : expm1f(o1);
    unsigned short h0, l0, h1, l1;
    split2(o0, h0, l0); split2(o1, h1, l1);
    unsigned short* o = h2 + (size_t)node * (2 * HC) + (ch >> 3) * 16 + (ch & 7);
    o[0] = h0; o[1] = h1; o[8] = l0; o[9] = l1;
}

// ---------------------------------------------------------------------------
// Pool stage 1: per (graph, quarter) partial sums (deterministic, no atomics)
// ---------------------------------------------------------------------------
__global__ __launch_bounds__(256) void pool_part_kernel(const unsigned short* __restrict__ h2,
                                                        const int* __restrict__ batch,
                                                        float* __restrict__ partial) {
    const int g = blockIdx.x, part = blockIdx.y;
    int lo = 0, hi = NODES;
    while (lo < hi) { int mid = (lo + hi) >> 1; if (batch[mid] < g) lo = mid + 1; else hi = mid; }
    const int s = lo;
    lo = s; hi = NODES;
    while (lo < hi) { int mid = (lo + hi) >> 1; if (batch[mid] < g + 1) lo = mid + 1; else hi = mid; }
    const int e = lo, cnt = e - s;
    const int ps = s + (cnt * part) / 4;
    const int pe = s + (cnt * (part + 1)) / 4;

    const int c0 = threadIdx.x * 2;
    const int boff = ((c0 >> 3) * 16) + (c0 & 7);
    float s0 = 0.f, s1 = 0.f;
    for (int r = ps; r < pe; ++r) {
        const unsigned short* p = h2 + (size_t)r * (2 * HC) + boff;
        s0 += bf16f(p[0]) + bf16f(p[8]);
        s1 += bf16f(p[1]) + bf16f(p[9]);
    }
    float* o = partial + ((size_t)(g * 4 + part)) * HC;
    o[c0] = s0; o[c0 + 1] = s1;
}

// ---------------------------------------------------------------------------
// Pool stage 2 + classifier
// ---------------------------------------------------------------------------
__global__ __launch_bounds__(256) void cls_kernel(const float* __restrict__ partial,
                                                  const int* __restrict__ batch,
                                                  const float* __restrict__ W,
                                                  const float* __restrict__ cb,
                                                  float* __restrict__ outp) {
    const int g = blockIdx.x;
    __shared__ float pooled[HC];
    int lo = 0, hi = NODES;
    while (lo < hi) { int mid = (lo + hi) >> 1; if (batch[mid] < g) lo = mid + 1; else hi = mid; }
    const int s = lo;
    lo = s; hi = NODES;
    while (lo < hi) { int mid = (lo + hi) >> 1; if (batch[mid] < g + 1) lo = mid + 1; else hi = mid; }
    const int cnt = lo - s;

    const int c0 = threadIdx.x * 2;
    float s0 = 0.f, s1 = 0.f;
    #pragma unroll
    for (int part = 0; part < 4; ++part) {
        const float* p = partial + ((size_t)(g * 4 + part)) * HC;
        s0 += p[c0]; s1 += p[c0 + 1];
    }
    const float invc = cnt > 0 ? 1.f / (float)cnt : 0.f;
    pooled[c0] = s0 * invc; pooled[c0 + 1] = s1 * invc;
    __syncthreads();

    const int lane = threadIdx.x & 63, wid = threadIdx.x >> 6;
    for (int o = wid; o < OUT_F; o += 4) {
        float p = 0.f;
        for (int c = lane; c < HC; c += 64) p += pooled[c] * W[c * OUT_F + o];
        #pragma unroll
        for (int off2 = 32; off2; off2 >>= 1) p += __shfl_xor(p, off2);
        if (lane == 0) outp[g * OUT_F + o] = p + cb[o];
    }
}

// ---------------------------------------------------------------------------
// Host-side launch
// ---------------------------------------------------------------------------
extern "C" void kernel_launch(void* const* d_in, const int* in_sizes, int n_in,
                              void* d_out, int out_size, void* d_ws, size_t ws_size,
                              hipStream_t stream) {
    const float* x      = (const float*)d_in[0];
    const int*   ei     = (const int*)d_in[1];
    const int*   batch  = (const int*)d_in[2];
    const float* pre_W  = (const float*)d_in[3];
    const float* pre_b  = (const float*)d_in[4];
    const float* cls_W  = (const float*)d_in[5];
    const float* cls_b  = (const float*)d_in[6];
    const float* Wl[3]; const float* bl[3]; const float* Wr[3];
    const float* br[3]; const float* attw[3]; const float* bw[3];
    for (int l = 0; l < 3; ++l) {
        Wl[l]   = (const float*)d_in[7 + 6 * l + 0];
        bl[l]   = (const float*)d_in[7 + 6 * l + 1];
        Wr[l]   = (const float*)d_in[7 + 6 * l + 2];
        br[l]   = (const float*)d_in[7 + 6 * l + 3];
        attw[l] = (const float*)d_in[7 + 6 * l + 4];
        bw[l]   = (const float*)d_in[7 + 6 * l + 5];
    }
    float* outp = (float*)d_out;

    // ---- workspace carve (~128 MB, lifetime-aliased) ----
    char* ws = (char*)d_ws;
    size_t off = 0;
    auto alloc = [&](size_t b) { char* p = ws + off; off += (b + 255) & ~(size_t)255; return p; };
    float* xlr = (float*)alloc((size_t)MPAD * XLRW * 4);                // 82.3 MB
    unsigned short* h2 = (unsigned short*)alloc((size_t)MPAD * 2 * HC * 2); // 41.2 MB
    unsigned short* WT2f = (unsigned short*)alloc((size_t)1024 * 2 * HC * 2); // 2.1 MB (K<=512)
    unsigned short* preWT2 = (unsigned short*)alloc((size_t)HID * 2 * IN_F * 2); // 131 KB
    float* biascat = (float*)alloc(3 * 1024 * 4);
    int* counts  = (int*)alloc(NODES * 4);
    int* offsets = (int*)alloc((NODES + 1) * 4);
    int* cursor  = (int*)alloc(NODES * 4);
    int* srcsb   = (int*)alloc((size_t)EPRIME * 4);
    // aliases (disjoint lifetimes):
    unsigned short* x2 = (unsigned short*)xlr;   // dead before xlr written (L1 GEMM)
    float* partial = xlr;                        // pool runs after xlr is dead

    // ---- edge sort ----
    hipMemsetAsync(counts, 0, NODES * 4, stream);
    hist_kernel<<<(EPRIME + 255) / 256, 256, 0, stream>>>(ei, counts);
    scan_kernel<<<1, 1024, 0, stream>>>(counts, offsets, cursor);
    scatter_kernel<<<(EPRIME + 255) / 256, 256, 0, stream>>>(ei, cursor, srcsb);

    // ---- conversions ----
    convert_x_kernel<<<(MPAD * (IN_F / 8) + 255) / 256, 256, 0, stream>>>(x, x2);
    convert_w_kernel<<<(HID * (IN_F / 8) + 255) / 256, 256, 0, stream>>>(pre_W, preWT2, IN_F, HID, 5);
    build_bias_kernel<<<12, 256, 0, stream>>>(bl[0], br[0], bl[1], br[1], bl[2], br[2], biascat);
    // layer 0 fused weights: rows 0..511 = Wl, rows 512..1023 = Wr (row stride 2*K shorts)
    convert_w_kernel<<<(HC * (HID / 8) + 255) / 256, 256, 0, stream>>>(Wl[0], WT2f, HID, HC, 4);
    convert_w_kernel<<<(HC * (HID / 8) + 255) / 256, 256, 0, stream>>>(Wr[0], WT2f + (size_t)512 * 2 * HID, HID, HC, 4);

    // ---- pre layer: h = elu(x @ pre_W + pre_b), split-written ----
    mfma_gemm_kernel<1, 1><<<dim3(157, 1), 256, 0, stream>>>(x2, preWT2, pre_b,
                                                             nullptr, h2, NODES, HID, IN_F);

    // ---- layer 1 (fused Wl|Wr GEMM, N=1024) ----
    mfma_gemm_kernel<0, 0><<<dim3(157, 8), 256, 0, stream>>>(h2, WT2f, biascat, xlr, nullptr, NODES, 1024, HID);
    convert_w_kernel<<<(HC * (HC / 8) + 255) / 256, 256, 0, stream>>>(Wl[1], WT2f, HC, HC, 6);
    convert_w_kernel<<<(HC * (HC / 8) + 255) / 256, 256, 0, stream>>>(Wr[1], WT2f + (size_t)512 * 2 * HC, HC, HC, 6);
    gat_edge_kernel<<<MPAD, 256, 0, stream>>>(xlr, attw[0], bw[0], offsets, srcsb, h2);

    // ---- layer 2 ----
    mfma_gemm_kernel<0, 0><<<dim3(157, 8), 256, 0, stream>>>(h2, WT2f, biascat + 1024, xlr, nullptr, NODES, 1024, HC);
    convert_w_kernel<<<(HC * (HC / 8) + 255) / 256, 256, 0, stream>>>(Wl[2], WT2f, HC, HC, 6);
    convert_w_kernel<<<(HC * (HC / 8) + 255) / 256, 256, 0, stream>>>(Wr[2], WT2f + (size_t)512 * 2 * HC, HC, HC, 6);
    gat_edge_kernel<<<MPAD, 256, 0, stream>>>(xlr, attw[1], bw[1], offsets, srcsb, h2);

    // ---- layer 3 ----
    mfma_gemm_kernel<0, 0><<<dim3(157, 8), 256, 0, stream>>>(h2, WT2f, biascat + 2048, xlr, nullptr, NODES, 1024, HC);
    gat_edge_kernel<<<MPAD, 256, 0, stream>>>(xlr, attw[2], bw[2], offsets, srcsb, h2);

    // ---- pool + classifier ----
    pool_part_kernel<<<dim3(NGRAPH, 4), 256, 0, stream>>>(h2, batch, partial);
    cls_kernel<<<NGRAPH, 256, 0, stream>>>(partial, batch, cls_W, cls_b, outp);
}